// Round 6
// baseline (2038.845 us; speedup 1.0000x reference)
//
#include <hip/hip_runtime.h>
#include <hip/hip_bf16.h>

// Flash-attention forward, B=4 H=16 S=2048 D=128, fp32 in/out, no 1/sqrt(D) scale.
// Round 5: T14 async-STAGE split (issue next tile's global loads early, cvt+ds_write
//   late) + T5 s_setprio around MFMA clusters. Structure otherwise round 4
//   (fp16 single-precision path, tr_read V, swizzled P).

#define QBLK   64
#define KVBLK  64
#define DHEAD  128
#define SEQ    2048
#define NT     (SEQ / KVBLK)
#define KPAD   136   // 128+8 f16 -> row stride 272 B
#define PPAD   72    // 64+8

typedef _Float16 f16x8 __attribute__((ext_vector_type(8)));
typedef _Float16 f16x4 __attribute__((ext_vector_type(4)));
typedef float    f32x4 __attribute__((ext_vector_type(4)));

__global__ __launch_bounds__(256, 3)
void attn_fwd_kernel(const float* __restrict__ Q, const float* __restrict__ K,
                     const float* __restrict__ V, float* __restrict__ O) {
    __shared__ __align__(16) _Float16 K_lds[KVBLK * KPAD];
    __shared__ __align__(16) _Float16 V_lds[KVBLK * DHEAD];   // subtiled [kv/4][d/16][4][16]
    __shared__ __align__(16) _Float16 P_lds[4 * 16 * PPAD];

    const int tid  = threadIdx.x;
    const int lane = tid & 63;
    const int wave = tid >> 6;
    const int g    = lane >> 4;   // lane-group 0..3
    const int lg   = lane & 15;

    const int qtile = blockIdx.x;
    const int bh    = blockIdx.y;
    const size_t base = (size_t)bh * SEQ * DHEAD;
    const float* Qg = Q + base + (size_t)(qtile * QBLK) * DHEAD;
    const float* Kg = K + base;
    const float* Vg = V + base;
    float*       Og = O + base + (size_t)(qtile * QBLK) * DHEAD;

    // per-lane base byte-address for ds_read_b64_tr_b16 on V_lds:
    //   window (128B subtile) = kt*8192 + g*2048 + s*1024 + dt*128  (kt,s,dt via offset:)
    //   column within window  = lg  -> lane-offset lg*8 bytes
    const unsigned trbase = (unsigned)(size_t)&V_lds[0] + (unsigned)(g * 2048 + lg * 8);

    // staging address components (per thread, loop-invariant)
    const int c0   = tid;                 // j-th chunk adds 256*j
    // K: row = c>>4, dc = (c&15)*8
    // V: d8 = (c&1)|(((c>>3)&7)<<1), row = ((c>>1)&3)|((c>>6)<<2), d0 = d8*8

    // ---- Q fragments in registers (fp16). A-layout: row=lane&15, k=(lane>>4)*8+i
    f16x8 qf[4];
    {
        const float* qrow = Qg + (size_t)(wave * 16 + lg) * DHEAD;
        #pragma unroll
        for (int dc = 0; dc < 4; ++dc) {
            const int d0 = dc * 32 + g * 8;
            float4 f0 = *(const float4*)(qrow + d0);
            float4 f1 = *(const float4*)(qrow + d0 + 4);
            qf[dc][0] = (_Float16)f0.x; qf[dc][1] = (_Float16)f0.y;
            qf[dc][2] = (_Float16)f0.z; qf[dc][3] = (_Float16)f0.w;
            qf[dc][4] = (_Float16)f1.x; qf[dc][5] = (_Float16)f1.y;
            qf[dc][6] = (_Float16)f1.z; qf[dc][7] = (_Float16)f1.w;
        }
    }

    // ---- online-softmax state + output accumulators
    f32x4 acc[8];
    #pragma unroll
    for (int dt = 0; dt < 8; ++dt) { acc[dt][0]=0.f; acc[dt][1]=0.f; acc[dt][2]=0.f; acc[dt][3]=0.f; }
    float m[4], l[4];
    #pragma unroll
    for (int r = 0; r < 4; ++r) { m[r] = -1e30f; l[r] = 0.f; }

    // ---- T14 register staging buffers (next tile's raw fp32 data)
    float4 kreg[4][2], vreg[4][2];

    #define LOAD_TILE(T)                                                          \
    {                                                                             \
        const float* Kt = Kg + (size_t)(T) * KVBLK * DHEAD;                       \
        const float* Vt = Vg + (size_t)(T) * KVBLK * DHEAD;                       \
        _Pragma("unroll")                                                         \
        for (int j = 0; j < 4; ++j) {                                             \
            const int c    = c0 + 256 * j;                                        \
            const int krow = c >> 4;                                              \
            const int kdc  = (c & 15) * 8;                                        \
            kreg[j][0] = *(const float4*)(Kt + krow * DHEAD + kdc);               \
            kreg[j][1] = *(const float4*)(Kt + krow * DHEAD + kdc + 4);           \
            const int d8   = (c & 1) | (((c >> 3) & 7) << 1);                     \
            const int vrow = ((c >> 1) & 3) | ((c >> 6) << 2);                    \
            const int d0   = d8 * 8;                                              \
            vreg[j][0] = *(const float4*)(Vt + vrow * DHEAD + d0);                \
            vreg[j][1] = *(const float4*)(Vt + vrow * DHEAD + d0 + 4);            \
        }                                                                         \
    }

    // prologue: tile 0 loads
    LOAD_TILE(0);

    for (int t = 0; t < NT; ++t) {
        // ---- write staged tile t to LDS (vmcnt wait auto-inserted on reg use)
        #pragma unroll
        for (int j = 0; j < 4; ++j) {
            const int c    = c0 + 256 * j;
            const int krow = c >> 4;
            const int kdc  = (c & 15) * 8;
            float kf[8] = {kreg[j][0].x, kreg[j][0].y, kreg[j][0].z, kreg[j][0].w,
                           kreg[j][1].x, kreg[j][1].y, kreg[j][1].z, kreg[j][1].w};
            f16x8 vh;
            #pragma unroll
            for (int i = 0; i < 8; ++i) vh[i] = (_Float16)kf[i];
            *(f16x8*)&K_lds[krow * KPAD + kdc] = vh;

            const int d8   = (c & 1) | (((c >> 3) & 7) << 1);
            const int vrow = ((c >> 1) & 3) | ((c >> 6) << 2);
            const int d0   = d8 * 8;
            float vf[8] = {vreg[j][0].x, vreg[j][0].y, vreg[j][0].z, vreg[j][0].w,
                           vreg[j][1].x, vreg[j][1].y, vreg[j][1].z, vreg[j][1].w};
            f16x8 vv;
            #pragma unroll
            for (int i = 0; i < 8; ++i) vv[i] = (_Float16)vf[i];
            const int st = (vrow >> 2) * 8 + (d0 >> 4);
            *(f16x8*)&V_lds[st * 64 + (vrow & 3) * 16 + (d0 & 15)] = vv;
        }
        __syncthreads();

        // ---- issue next tile's global loads (latency hidden under compute below)
        if (t + 1 < NT) LOAD_TILE(t + 1);
        __builtin_amdgcn_sched_barrier(0);   // pin loads above the compute

        // ---- S = Q * K^T (16 q-rows x 64 kv-cols per wave)
        f32x4 s[4];
        __builtin_amdgcn_s_setprio(1);
        #pragma unroll
        for (int ct = 0; ct < 4; ++ct) {
            f32x4 a; a[0]=0.f; a[1]=0.f; a[2]=0.f; a[3]=0.f;
            #pragma unroll
            for (int dc = 0; dc < 4; ++dc) {
                const int off = (ct * 16 + lg) * KPAD + dc * 32 + g * 8;
                f16x8 kh = *(const f16x8*)&K_lds[off];
                a = __builtin_amdgcn_mfma_f32_16x16x32_f16(qf[dc], kh, a, 0, 0, 0);
            }
            s[ct] = a;
        }
        __builtin_amdgcn_s_setprio(0);

        // ---- online softmax (per q-row r; row lives in 16-lane group)
        #pragma unroll
        for (int r = 0; r < 4; ++r) {
            float rowmax = fmaxf(fmaxf(s[0][r], s[1][r]), fmaxf(s[2][r], s[3][r]));
            #pragma unroll
            for (int off = 1; off < 16; off <<= 1)
                rowmax = fmaxf(rowmax, __shfl_xor(rowmax, off));
            const float mnew = fmaxf(m[r], rowmax);
            const float sc   = __expf(m[r] - mnew);
            m[r] = mnew;
            float rs = 0.f;
            #pragma unroll
            for (int ct = 0; ct < 4; ++ct) {
                float p = __expf(s[ct][r] - mnew);
                s[ct][r] = p;
                rs += p;
            }
            #pragma unroll
            for (int off = 1; off < 16; off <<= 1)
                rs += __shfl_xor(rs, off);
            l[r] = l[r] * sc + rs;
            #pragma unroll
            for (int dt = 0; dt < 8; ++dt) acc[dt][r] *= sc;
        }

        // ---- P (C/D layout) -> LDS (XOR-swizzled) -> A-fragment layout
        _Float16* pbase = &P_lds[wave * 16 * PPAD];
        #pragma unroll
        for (int ct = 0; ct < 4; ++ct)
            #pragma unroll
            for (int r = 0; r < 4; ++r)
                pbase[(g * 4 + r) * PPAD + ((ct * 16 + lg) ^ (g << 3))] = (_Float16)s[ct][r];

        // ---- O += P * V  (V via ds_read_b64_tr_b16 from subtiled layout)
        #pragma unroll
        for (int kt = 0; kt < 2; ++kt) {
            f16x8 pf = *(const f16x8*)&pbase[lg * PPAD + ((kt * 32 + g * 8) ^ ((lg >> 2) << 3))];
            #pragma unroll
            for (int dp = 0; dp < 4; ++dp) {
                f16x4 a0, a1, b0, b1;
                asm volatile(
                    "ds_read_b64_tr_b16 %0, %4 offset:%5\n\t"
                    "ds_read_b64_tr_b16 %1, %4 offset:%6\n\t"
                    "ds_read_b64_tr_b16 %2, %4 offset:%7\n\t"
                    "ds_read_b64_tr_b16 %3, %4 offset:%8\n\t"
                    "s_waitcnt lgkmcnt(0)"
                    : "=&v"(a0), "=&v"(a1), "=&v"(b0), "=&v"(b1)
                    : "v"(trbase),
                      "i"(kt * 8192 + (dp * 2 + 0) * 128),
                      "i"(kt * 8192 + 1024 + (dp * 2 + 0) * 128),
                      "i"(kt * 8192 + (dp * 2 + 1) * 128),
                      "i"(kt * 8192 + 1024 + (dp * 2 + 1) * 128)
                    : "memory");
                __builtin_amdgcn_sched_barrier(0);
                f16x8 vf0 = __builtin_shufflevector(a0, a1, 0, 1, 2, 3, 4, 5, 6, 7);
                f16x8 vf1 = __builtin_shufflevector(b0, b1, 0, 1, 2, 3, 4, 5, 6, 7);
                __builtin_amdgcn_s_setprio(1);
                acc[dp * 2 + 0] = __builtin_amdgcn_mfma_f32_16x16x32_f16(pf, vf0, acc[dp * 2 + 0], 0, 0, 0);
                acc[dp * 2 + 1] = __builtin_amdgcn_mfma_f32_16x16x32_f16(pf, vf1, acc[dp * 2 + 1], 0, 0, 0);
                __builtin_amdgcn_s_setprio(0);
            }
        }
        __syncthreads();
    }

    // ---- epilogue: O / l
    float inv[4];
    #pragma unroll
    for (int r = 0; r < 4; ++r) inv[r] = 1.f / l[r];
    float* ob = Og + (size_t)(wave * 16) * DHEAD;
    #pragma unroll
    for (int dt = 0; dt < 8; ++dt)
        #pragma unroll
        for (int r = 0; r < 4; ++r)
            ob[(size_t)(g * 4 + r) * DHEAD + dt * 16 + lg] = acc[dt][r] * inv[r];
}

extern "C" void kernel_launch(void* const* d_in, const int* in_sizes, int n_in,
                              void* d_out, int out_size, void* d_ws, size_t ws_size,
                              hipStream_t stream) {
    const float* q = (const float*)d_in[0];
    const float* k = (const float*)d_in[1];
    const float* v = (const float*)d_in[2];
    float* out = (float*)d_out;
    const int BH = in_sizes[0] / (SEQ * DHEAD);   // 64
    dim3 grid(SEQ / QBLK, BH);
    attn_fwd_kernel<<<grid, dim3(256), 0, stream>>>(q, k, v, out);
}

// Round 7
// 679.367 us; speedup vs baseline: 3.0011x; 3.0011x over previous
//
#include <hip/hip_runtime.h>
#include <hip/hip_bf16.h>

// Flash-attention forward, B=4 H=16 S=2048 D=128, fp32 in/out, no 1/sqrt(D) scale.
// Round 6: revert R5's reg-staging (it spilled -> 3.8GB scratch writes).
//   Back to R4 structure, but QBLK=128: each wave owns 32 q-rows (2x 16-row
//   subtiles), so K ds_reads / V tr_reads / staging / fetch amortize over 2x work.

#define QBLK   128
#define KVBLK  64
#define DHEAD  128
#define SEQ    2048
#define KPAD   136   // 128+8 f16 -> row stride 272 B
#define PPAD   72    // 64+8

typedef _Float16 f16x8 __attribute__((ext_vector_type(8)));
typedef _Float16 f16x4 __attribute__((ext_vector_type(4)));
typedef float    f32x4 __attribute__((ext_vector_type(4)));

__global__ __launch_bounds__(256, 3)
void attn_fwd_kernel(const float* __restrict__ Q, const float* __restrict__ K,
                     const float* __restrict__ V, float* __restrict__ O) {
    __shared__ __align__(16) _Float16 K_lds[KVBLK * KPAD];
    __shared__ __align__(16) _Float16 V_lds[KVBLK * DHEAD];   // subtiled [kv/4][d/16][4][16]
    __shared__ __align__(16) _Float16 P_lds[4 * 32 * PPAD];

    const int tid  = threadIdx.x;
    const int lane = tid & 63;
    const int wave = tid >> 6;
    const int g    = lane >> 4;   // lane-group 0..3
    const int lg   = lane & 15;

    const int qtile = blockIdx.x;
    const int bh    = blockIdx.y;
    const size_t base = (size_t)bh * SEQ * DHEAD;
    const float* Qg = Q + base + (size_t)(qtile * QBLK) * DHEAD;
    const float* Kg = K + base;
    const float* Vg = V + base;
    float*       Og = O + base + (size_t)(qtile * QBLK) * DHEAD;

    // per-lane base byte-address for ds_read_b64_tr_b16 on V_lds:
    //   window (128B subtile) = kt*8192 + g*2048 + s*1024 + dt*128  (via offset:)
    //   column within window  = lg  -> lane-offset lg*8 bytes
    const unsigned trbase = (unsigned)(size_t)&V_lds[0] + (unsigned)(g * 2048 + lg * 8);

    // ---- Q fragments (fp16), 2 row-subtiles. A-layout: row=lane&15, k=(lane>>4)*8+i
    f16x8 qf[2][4];
    #pragma unroll
    for (int r16 = 0; r16 < 2; ++r16) {
        const float* qrow = Qg + (size_t)(wave * 32 + r16 * 16 + lg) * DHEAD;
        #pragma unroll
        for (int dc = 0; dc < 4; ++dc) {
            const int d0 = dc * 32 + g * 8;
            float4 f0 = *(const float4*)(qrow + d0);
            float4 f1 = *(const float4*)(qrow + d0 + 4);
            qf[r16][dc][0] = (_Float16)f0.x; qf[r16][dc][1] = (_Float16)f0.y;
            qf[r16][dc][2] = (_Float16)f0.z; qf[r16][dc][3] = (_Float16)f0.w;
            qf[r16][dc][4] = (_Float16)f1.x; qf[r16][dc][5] = (_Float16)f1.y;
            qf[r16][dc][6] = (_Float16)f1.z; qf[r16][dc][7] = (_Float16)f1.w;
        }
    }

    // ---- online-softmax state + output accumulators
    f32x4 acc[2][8];
    #pragma unroll
    for (int r16 = 0; r16 < 2; ++r16)
        #pragma unroll
        for (int dt = 0; dt < 8; ++dt) { acc[r16][dt][0]=0.f; acc[r16][dt][1]=0.f; acc[r16][dt][2]=0.f; acc[r16][dt][3]=0.f; }
    float m[2][4], l[2][4];
    #pragma unroll
    for (int r16 = 0; r16 < 2; ++r16)
        #pragma unroll
        for (int r = 0; r < 4; ++r) { m[r16][r] = -1e30f; l[r16][r] = 0.f; }

    for (int t = 0; t < SEQ / KVBLK; ++t) {
        // ---- stage K tile (row-major fp16, padded; <=2-way banks)
        {
            const float* Kt = Kg + (size_t)t * KVBLK * DHEAD;
            #pragma unroll
            for (int j = 0; j < 4; ++j) {
                const int c   = tid + 256 * j;      // 0..1023
                const int row = c >> 4;
                const int dc  = (c & 15) * 8;
                float4 f0 = *(const float4*)(Kt + row * DHEAD + dc);
                float4 f1 = *(const float4*)(Kt + row * DHEAD + dc + 4);
                f16x8 vh;
                vh[0]=(_Float16)f0.x; vh[1]=(_Float16)f0.y; vh[2]=(_Float16)f0.z; vh[3]=(_Float16)f0.w;
                vh[4]=(_Float16)f1.x; vh[5]=(_Float16)f1.y; vh[6]=(_Float16)f1.z; vh[7]=(_Float16)f1.w;
                *(f16x8*)&K_lds[row * KPAD + dc] = vh;
            }
            // ---- stage V tile into subtiled layout [kv/4][d/16][4][16]
            const float* Vt = Vg + (size_t)t * KVBLK * DHEAD;
            #pragma unroll
            for (int j = 0; j < 4; ++j) {
                const int c   = tid + 256 * j;                 // 0..1023
                const int d8  = (c & 1) | (((c >> 3) & 7) << 1);   // 0..15
                const int row = ((c >> 1) & 3) | ((c >> 6) << 2);  // 0..63
                const int d0  = d8 * 8;
                float4 f0 = *(const float4*)(Vt + row * DHEAD + d0);
                float4 f1 = *(const float4*)(Vt + row * DHEAD + d0 + 4);
                f16x8 vv;
                vv[0]=(_Float16)f0.x; vv[1]=(_Float16)f0.y; vv[2]=(_Float16)f0.z; vv[3]=(_Float16)f0.w;
                vv[4]=(_Float16)f1.x; vv[5]=(_Float16)f1.y; vv[6]=(_Float16)f1.z; vv[7]=(_Float16)f1.w;
                const int st = (row >> 2) * 8 + (d0 >> 4);
                *(f16x8*)&V_lds[st * 64 + (row & 3) * 16 + (d0 & 15)] = vv;
            }
        }
        __syncthreads();

        // ---- S = Q * K^T: each K fragment read once, feeds both row-subtiles
        f32x4 s[2][4];
        #pragma unroll
        for (int ct = 0; ct < 4; ++ct) {
            f32x4 a0; a0[0]=0.f; a0[1]=0.f; a0[2]=0.f; a0[3]=0.f;
            f32x4 a1 = a0;
            #pragma unroll
            for (int dc = 0; dc < 4; ++dc) {
                const int off = (ct * 16 + lg) * KPAD + dc * 32 + g * 8;
                f16x8 kh = *(const f16x8*)&K_lds[off];
                a0 = __builtin_amdgcn_mfma_f32_16x16x32_f16(qf[0][dc], kh, a0, 0, 0, 0);
                a1 = __builtin_amdgcn_mfma_f32_16x16x32_f16(qf[1][dc], kh, a1, 0, 0, 0);
            }
            s[0][ct] = a0; s[1][ct] = a1;
        }

        // ---- online softmax (per subtile, per q-row r in 16-lane group)
        #pragma unroll
        for (int r16 = 0; r16 < 2; ++r16) {
            #pragma unroll
            for (int r = 0; r < 4; ++r) {
                float rowmax = fmaxf(fmaxf(s[r16][0][r], s[r16][1][r]), fmaxf(s[r16][2][r], s[r16][3][r]));
                #pragma unroll
                for (int off = 1; off < 16; off <<= 1)
                    rowmax = fmaxf(rowmax, __shfl_xor(rowmax, off));
                const float mnew = fmaxf(m[r16][r], rowmax);
                const float sc   = __expf(m[r16][r] - mnew);
                m[r16][r] = mnew;
                float rs = 0.f;
                #pragma unroll
                for (int ct = 0; ct < 4; ++ct) {
                    float p = __expf(s[r16][ct][r] - mnew);
                    s[r16][ct][r] = p;
                    rs += p;
                }
                #pragma unroll
                for (int off = 1; off < 16; off <<= 1)
                    rs += __shfl_xor(rs, off);
                l[r16][r] = l[r16][r] * sc + rs;
                #pragma unroll
                for (int dt = 0; dt < 8; ++dt) acc[r16][dt][r] *= sc;
            }
        }

        // ---- P (C/D layout) -> LDS (XOR-swizzled) -> A-fragment layout
        _Float16* pbase = &P_lds[wave * 32 * PPAD];
        #pragma unroll
        for (int r16 = 0; r16 < 2; ++r16)
            #pragma unroll
            for (int ct = 0; ct < 4; ++ct)
                #pragma unroll
                for (int r = 0; r < 4; ++r)
                    pbase[(r16 * 16 + g * 4 + r) * PPAD + ((ct * 16 + lg) ^ (g << 3))] = (_Float16)s[r16][ct][r];

        // ---- O += P * V  (each V tr_read feeds both row-subtiles)
        #pragma unroll
        for (int kt = 0; kt < 2; ++kt) {
            f16x8 pf0 = *(const f16x8*)&pbase[lg * PPAD + ((kt * 32 + g * 8) ^ ((lg >> 2) << 3))];
            f16x8 pf1 = *(const f16x8*)&pbase[(16 + lg) * PPAD + ((kt * 32 + g * 8) ^ ((lg >> 2) << 3))];
            #pragma unroll
            for (int dp = 0; dp < 4; ++dp) {
                f16x4 a0, a1, b0, b1;
                asm volatile(
                    "ds_read_b64_tr_b16 %0, %4 offset:%5\n\t"
                    "ds_read_b64_tr_b16 %1, %4 offset:%6\n\t"
                    "ds_read_b64_tr_b16 %2, %4 offset:%7\n\t"
                    "ds_read_b64_tr_b16 %3, %4 offset:%8\n\t"
                    "s_waitcnt lgkmcnt(0)"
                    : "=&v"(a0), "=&v"(a1), "=&v"(b0), "=&v"(b1)
                    : "v"(trbase),
                      "i"(kt * 8192 + (dp * 2 + 0) * 128),
                      "i"(kt * 8192 + 1024 + (dp * 2 + 0) * 128),
                      "i"(kt * 8192 + (dp * 2 + 1) * 128),
                      "i"(kt * 8192 + 1024 + (dp * 2 + 1) * 128)
                    : "memory");
                __builtin_amdgcn_sched_barrier(0);
                f16x8 vf0 = __builtin_shufflevector(a0, a1, 0, 1, 2, 3, 4, 5, 6, 7);
                f16x8 vf1 = __builtin_shufflevector(b0, b1, 0, 1, 2, 3, 4, 5, 6, 7);
                acc[0][dp * 2 + 0] = __builtin_amdgcn_mfma_f32_16x16x32_f16(pf0, vf0, acc[0][dp * 2 + 0], 0, 0, 0);
                acc[0][dp * 2 + 1] = __builtin_amdgcn_mfma_f32_16x16x32_f16(pf0, vf1, acc[0][dp * 2 + 1], 0, 0, 0);
                acc[1][dp * 2 + 0] = __builtin_amdgcn_mfma_f32_16x16x32_f16(pf1, vf0, acc[1][dp * 2 + 0], 0, 0, 0);
                acc[1][dp * 2 + 1] = __builtin_amdgcn_mfma_f32_16x16x32_f16(pf1, vf1, acc[1][dp * 2 + 1], 0, 0, 0);
            }
        }
        __syncthreads();
    }

    // ---- epilogue: O / l
    #pragma unroll
    for (int r16 = 0; r16 < 2; ++r16) {
        float inv[4];
        #pragma unroll
        for (int r = 0; r < 4; ++r) inv[r] = 1.f / l[r16][r];
        float* ob = Og + (size_t)(wave * 32 + r16 * 16) * DHEAD;
        #pragma unroll
        for (int dt = 0; dt < 8; ++dt)
            #pragma unroll
            for (int r = 0; r < 4; ++r)
                ob[(size_t)(g * 4 + r) * DHEAD + dt * 16 + lg] = acc[r16][dt][r] * inv[r];
    }
}

extern "C" void kernel_launch(void* const* d_in, const int* in_sizes, int n_in,
                              void* d_out, int out_size, void* d_ws, size_t ws_size,
                              hipStream_t stream) {
    const float* q = (const float*)d_in[0];
    const float* k = (const float*)d_in[1];
    const float* v = (const float*)d_in[2];
    float* out = (float*)d_out;
    const int BH = in_sizes[0] / (SEQ * DHEAD);   // 64
    dim3 grid(SEQ / QBLK, BH);
    attn_fwd_kernel<<<grid, dim3(256), 0, stream>>>(q, k, v, out);
}

// Round 8
// 339.664 us; speedup vs baseline: 6.0025x; 2.0001x over previous
//
#include <hip/hip_runtime.h>
#include <hip/hip_bf16.h>

// Flash-attention forward, B=4 H=16 S=2048 D=128, fp32 in/out, no 1/sqrt(D) scale.
// Round 7: revert to R4 structure (355us). Add:
//   (1) XCD-gather block swizzle: all 32 q-tiles of a head land on one XCD
//       -> K/V becomes L2-resident (FETCH 557MB -> ~300MB predicted).
//   (2) T5 s_setprio around MFMA clusters.

#define QBLK   64
#define KVBLK  64
#define DHEAD  128
#define SEQ    2048
#define KPAD   136   // 128+8 f16 -> row stride 272 B
#define PPAD   72    // 64+8

typedef _Float16 f16x8 __attribute__((ext_vector_type(8)));
typedef _Float16 f16x4 __attribute__((ext_vector_type(4)));
typedef float    f32x4 __attribute__((ext_vector_type(4)));

__global__ __launch_bounds__(256, 3)
void attn_fwd_kernel(const float* __restrict__ Q, const float* __restrict__ K,
                     const float* __restrict__ V, float* __restrict__ O) {
    __shared__ __align__(16) _Float16 K_lds[KVBLK * KPAD];
    __shared__ __align__(16) _Float16 V_lds[KVBLK * DHEAD];   // subtiled [kv/4][d/16][4][16]
    __shared__ __align__(16) _Float16 P_lds[4 * 16 * PPAD];

    const int tid  = threadIdx.x;
    const int lane = tid & 63;
    const int wave = tid >> 6;
    const int g    = lane >> 4;   // lane-group 0..3
    const int lg   = lane & 15;

    // ---- XCD-gather swizzle: default dispatch round-robins flat%8 across XCDs.
    //      Remap so each XCD gets 8 whole heads (all their q-tiles) contiguously.
    const int flat    = blockIdx.x + gridDim.x * blockIdx.y;   // 0..2047
    const int newflat = (flat & 7) * 256 + (flat >> 3);        // bijective (2048 = 8*256)
    const int qtile   = newflat & 31;
    const int bh      = newflat >> 5;

    const size_t base = (size_t)bh * SEQ * DHEAD;
    const float* Qg = Q + base + (size_t)(qtile * QBLK) * DHEAD;
    const float* Kg = K + base;
    const float* Vg = V + base;
    float*       Og = O + base + (size_t)(qtile * QBLK) * DHEAD;

    // per-lane base byte-address for ds_read_b64_tr_b16 on V_lds:
    //   window (128B subtile) = kt*8192 + g*2048 + s*1024 + dt*128  (via offset:)
    //   column within window  = lg  -> lane-offset lg*8 bytes
    const unsigned trbase = (unsigned)(size_t)&V_lds[0] + (unsigned)(g * 2048 + lg * 8);

    // ---- Q fragments in registers (fp16). A-layout: row=lane&15, k=(lane>>4)*8+i
    f16x8 qf[4];
    {
        const float* qrow = Qg + (size_t)(wave * 16 + lg) * DHEAD;
        #pragma unroll
        for (int dc = 0; dc < 4; ++dc) {
            const int d0 = dc * 32 + g * 8;
            float4 f0 = *(const float4*)(qrow + d0);
            float4 f1 = *(const float4*)(qrow + d0 + 4);
            qf[dc][0] = (_Float16)f0.x; qf[dc][1] = (_Float16)f0.y;
            qf[dc][2] = (_Float16)f0.z; qf[dc][3] = (_Float16)f0.w;
            qf[dc][4] = (_Float16)f1.x; qf[dc][5] = (_Float16)f1.y;
            qf[dc][6] = (_Float16)f1.z; qf[dc][7] = (_Float16)f1.w;
        }
    }

    // ---- online-softmax state + output accumulators
    f32x4 acc[8];
    #pragma unroll
    for (int dt = 0; dt < 8; ++dt) { acc[dt][0]=0.f; acc[dt][1]=0.f; acc[dt][2]=0.f; acc[dt][3]=0.f; }
    float m[4], l[4];
    #pragma unroll
    for (int r = 0; r < 4; ++r) { m[r] = -1e30f; l[r] = 0.f; }

    for (int t = 0; t < SEQ / KVBLK; ++t) {
        // ---- stage K tile (row-major fp16, padded; <=2-way banks)
        {
            const float* Kt = Kg + (size_t)t * KVBLK * DHEAD;
            #pragma unroll
            for (int j = 0; j < 4; ++j) {
                const int c   = tid + 256 * j;      // 0..1023
                const int row = c >> 4;
                const int dc  = (c & 15) * 8;
                float4 f0 = *(const float4*)(Kt + row * DHEAD + dc);
                float4 f1 = *(const float4*)(Kt + row * DHEAD + dc + 4);
                f16x8 vh;
                vh[0]=(_Float16)f0.x; vh[1]=(_Float16)f0.y; vh[2]=(_Float16)f0.z; vh[3]=(_Float16)f0.w;
                vh[4]=(_Float16)f1.x; vh[5]=(_Float16)f1.y; vh[6]=(_Float16)f1.z; vh[7]=(_Float16)f1.w;
                *(f16x8*)&K_lds[row * KPAD + dc] = vh;
            }
            // ---- stage V tile into subtiled layout [kv/4][d/16][4][16]
            const float* Vt = Vg + (size_t)t * KVBLK * DHEAD;
            #pragma unroll
            for (int j = 0; j < 4; ++j) {
                const int c   = tid + 256 * j;                 // 0..1023
                const int d8  = (c & 1) | (((c >> 3) & 7) << 1);   // 0..15
                const int row = ((c >> 1) & 3) | ((c >> 6) << 2);  // 0..63
                const int d0  = d8 * 8;
                float4 f0 = *(const float4*)(Vt + row * DHEAD + d0);
                float4 f1 = *(const float4*)(Vt + row * DHEAD + d0 + 4);
                f16x8 vv;
                vv[0]=(_Float16)f0.x; vv[1]=(_Float16)f0.y; vv[2]=(_Float16)f0.z; vv[3]=(_Float16)f0.w;
                vv[4]=(_Float16)f1.x; vv[5]=(_Float16)f1.y; vv[6]=(_Float16)f1.z; vv[7]=(_Float16)f1.w;
                const int st = (row >> 2) * 8 + (d0 >> 4);
                *(f16x8*)&V_lds[st * 64 + (row & 3) * 16 + (d0 & 15)] = vv;
            }
        }
        __syncthreads();

        // ---- S = Q * K^T (16 q-rows x 64 kv-cols per wave)
        f32x4 s[4];
        __builtin_amdgcn_s_setprio(1);
        #pragma unroll
        for (int ct = 0; ct < 4; ++ct) {
            f32x4 a; a[0]=0.f; a[1]=0.f; a[2]=0.f; a[3]=0.f;
            #pragma unroll
            for (int dc = 0; dc < 4; ++dc) {
                const int off = (ct * 16 + lg) * KPAD + dc * 32 + g * 8;
                f16x8 kh = *(const f16x8*)&K_lds[off];
                a = __builtin_amdgcn_mfma_f32_16x16x32_f16(qf[dc], kh, a, 0, 0, 0);
            }
            s[ct] = a;
        }
        __builtin_amdgcn_s_setprio(0);

        // ---- online softmax (per q-row r; row lives in 16-lane group)
        #pragma unroll
        for (int r = 0; r < 4; ++r) {
            float rowmax = fmaxf(fmaxf(s[0][r], s[1][r]), fmaxf(s[2][r], s[3][r]));
            #pragma unroll
            for (int off = 1; off < 16; off <<= 1)
                rowmax = fmaxf(rowmax, __shfl_xor(rowmax, off));
            const float mnew = fmaxf(m[r], rowmax);
            const float sc   = __expf(m[r] - mnew);
            m[r] = mnew;
            float rs = 0.f;
            #pragma unroll
            for (int ct = 0; ct < 4; ++ct) {
                float p = __expf(s[ct][r] - mnew);
                s[ct][r] = p;
                rs += p;
            }
            #pragma unroll
            for (int off = 1; off < 16; off <<= 1)
                rs += __shfl_xor(rs, off);
            l[r] = l[r] * sc + rs;
            #pragma unroll
            for (int dt = 0; dt < 8; ++dt) acc[dt][r] *= sc;
        }

        // ---- P (C/D layout) -> LDS (XOR-swizzled) -> A-fragment layout
        _Float16* pbase = &P_lds[wave * 16 * PPAD];
        #pragma unroll
        for (int ct = 0; ct < 4; ++ct)
            #pragma unroll
            for (int r = 0; r < 4; ++r)
                pbase[(g * 4 + r) * PPAD + ((ct * 16 + lg) ^ (g << 3))] = (_Float16)s[ct][r];

        // ---- O += P * V  (V via ds_read_b64_tr_b16 from subtiled layout)
        #pragma unroll
        for (int kt = 0; kt < 2; ++kt) {
            f16x8 pf = *(const f16x8*)&pbase[lg * PPAD + ((kt * 32 + g * 8) ^ ((lg >> 2) << 3))];
            #pragma unroll
            for (int dp = 0; dp < 4; ++dp) {
                f16x4 a0, a1, b0, b1;
                asm volatile(
                    "ds_read_b64_tr_b16 %0, %4 offset:%5\n\t"
                    "ds_read_b64_tr_b16 %1, %4 offset:%6\n\t"
                    "ds_read_b64_tr_b16 %2, %4 offset:%7\n\t"
                    "ds_read_b64_tr_b16 %3, %4 offset:%8\n\t"
                    "s_waitcnt lgkmcnt(0)"
                    : "=&v"(a0), "=&v"(a1), "=&v"(b0), "=&v"(b1)
                    : "v"(trbase),
                      "i"(kt * 8192 + (dp * 2 + 0) * 128),
                      "i"(kt * 8192 + 1024 + (dp * 2 + 0) * 128),
                      "i"(kt * 8192 + (dp * 2 + 1) * 128),
                      "i"(kt * 8192 + 1024 + (dp * 2 + 1) * 128)
                    : "memory");
                __builtin_amdgcn_sched_barrier(0);
                f16x8 vf0 = __builtin_shufflevector(a0, a1, 0, 1, 2, 3, 4, 5, 6, 7);
                f16x8 vf1 = __builtin_shufflevector(b0, b1, 0, 1, 2, 3, 4, 5, 6, 7);
                __builtin_amdgcn_s_setprio(1);
                acc[dp * 2 + 0] = __builtin_amdgcn_mfma_f32_16x16x32_f16(pf, vf0, acc[dp * 2 + 0], 0, 0, 0);
                acc[dp * 2 + 1] = __builtin_amdgcn_mfma_f32_16x16x32_f16(pf, vf1, acc[dp * 2 + 1], 0, 0, 0);
                __builtin_amdgcn_s_setprio(0);
            }
        }
        __syncthreads();
    }

    // ---- epilogue: O / l
    float inv[4];
    #pragma unroll
    for (int r = 0; r < 4; ++r) inv[r] = 1.f / l[r];
    float* ob = Og + (size_t)(wave * 16) * DHEAD;
    #pragma unroll
    for (int dt = 0; dt < 8; ++dt)
        #pragma unroll
        for (int r = 0; r < 4; ++r)
            ob[(size_t)(g * 4 + r) * DHEAD + dt * 16 + lg] = acc[dt][r] * inv[r];
}

extern "C" void kernel_launch(void* const* d_in, const int* in_sizes, int n_in,
                              void* d_out, int out_size, void* d_ws, size_t ws_size,
                              hipStream_t stream) {
    const float* q = (const float*)d_in[0];
    const float* k = (const float*)d_in[1];
    const float* v = (const float*)d_in[2];
    float* out = (float*)d_out;
    const int BH = in_sizes[0] / (SEQ * DHEAD);   // 64
    dim3 grid(SEQ / QBLK, BH);
    attn_fwd_kernel<<<grid, dim3(256), 0, stream>>>(q, k, v, out);
}